// Round 8
// baseline (391.816 us; speedup 1.0000x reference)
//
#include <hip/hip_runtime.h>
#include <hip/hip_bf16.h>

#define NROW 8192
#define FIN  512
#define FOUT 64
#define NHEAD 4

constexpr float LOG2E = 1.44269504088896f;

typedef float f32x4 __attribute__((ext_vector_type(4)));
typedef int   i32x4 __attribute__((ext_vector_type(4)));
typedef unsigned u32x4 __attribute__((ext_vector_type(4)));
typedef __bf16 bf16x8 __attribute__((ext_vector_type(8)));

__device__ __forceinline__ unsigned bf_bits(float x) {
  unsigned u = __float_as_uint(x);
  u += 0x7FFF + ((u >> 16) & 1);          // round-to-nearest-even
  return u >> 16;
}

// ---------------------------------------------------------------------------
// K0: WT[hd][o][f] = bf16(W[hd][f][o])
// ---------------------------------------------------------------------------
__global__ __launch_bounds__(256) void wt_build(
    const float* __restrict__ W, __hip_bfloat16* __restrict__ WT)
{
  int t = blockIdx.x * 256 + threadIdx.x;
  int hd = t >> 9, f = t & 511;
  const float* wp = W + (hd * FIN + f) * FOUT;
#pragma unroll 8
  for (int o = 0; o < FOUT; ++o)
    WT[(hd * FOUT + o) * FIN + f] = __float2bfloat16(wp[o]);
}

// ---------------------------------------------------------------------------
// K1: h = x*W via MFMA (verified structure). Emits hT, f1, and the PACKED
// per-column table ED[hd][n] = (bf16(exp2(f2c)) << 16) | bf16(exp2(.2*f2c)).
// ---------------------------------------------------------------------------
__global__ __launch_bounds__(256) void gat_proj(
    const float* __restrict__ x, const __hip_bfloat16* __restrict__ WT,
    const float* __restrict__ a1, const float* __restrict__ a2,
    __hip_bfloat16* __restrict__ hT, float* __restrict__ f1,
    unsigned* __restrict__ ED)
{
  const int tid = threadIdx.x;
  const int wid = tid >> 6, lane = tid & 63;
  const int il = lane & 15, kg = lane >> 4;
  const int hd = blockIdx.x & 3;
  const int rg = blockIdx.x >> 2;
  const int n0 = rg * 64;

  __shared__ __align__(16) __hip_bfloat16 wt_lds[64 * 512];   // 64 KB
  __shared__ __align__(16) __hip_bfloat16 ht_tile[64 * 66];   // 8.25 KB

  {
    const int o = tid >> 2, q = tid & 3;
    const __hip_bfloat16* src = WT + (size_t)(hd * FOUT + o) * FIN;
#pragma unroll
    for (int k = 0; k < 16; ++k) {
      int u = q * 16 + k;
      bf16x8 vv = *(const bf16x8*)(src + u * 8);
      *(bf16x8*)(&wt_lds[o * 512 + (u ^ (o & 7)) * 8]) = vv;
    }
  }
  __syncthreads();

  const int n = n0 + wid * 16 + il;
  const float* xp = x + (size_t)n * FIN + kg * 8;

  f32x4 acc[4];
#pragma unroll
  for (int c = 0; c < 4; ++c) { f32x4 z = {0.f,0.f,0.f,0.f}; acc[c] = z; }

#pragma unroll 4
  for (int kk = 0; kk < FIN / 32; ++kk) {
    f32x4 xl = *(const f32x4*)(xp + kk * 32);
    f32x4 xh = *(const f32x4*)(xp + kk * 32 + 4);
    bf16x8 xb;
#pragma unroll
    for (int e = 0; e < 4; ++e) {
      xb[e]     = (__bf16)xl[e];
      xb[4 + e] = (__bf16)xh[e];
    }
#pragma unroll
    for (int c = 0; c < 4; ++c) {
      const int o = c * 16 + il;
      bf16x8 af = *(const bf16x8*)(
          &wt_lds[o * 512 + ((kk * 4 + kg) ^ (il & 7)) * 8]);
      acc[c] = __builtin_amdgcn_mfma_f32_16x16x32_bf16(af, xb, acc[c], 0, 0, 0);
    }
  }

  float p1 = 0.f, p2 = 0.f;
#pragma unroll
  for (int c = 0; c < 4; ++c) {
    f32x4 a1v = *(const f32x4*)(a1 + hd * FOUT + c * 16 + kg * 4);
    f32x4 a2v = *(const f32x4*)(a2 + hd * FOUT + c * 16 + kg * 4);
#pragma unroll
    for (int r = 0; r < 4; ++r) {
      p1 = fmaf(acc[c][r], a1v[r], p1);
      p2 = fmaf(acc[c][r], a2v[r], p2);
    }
  }
  p1 += __shfl_xor(p1, 16); p1 += __shfl_xor(p1, 32);
  p2 += __shfl_xor(p2, 16); p2 += __shfl_xor(p2, 32);
  if (kg == 0) {
    float f1c = p1 * LOG2E;
    float f2c = p2 * LOG2E;
    f1[hd * NROW + n] = f1c;
    float e2 = __builtin_amdgcn_exp2f(f2c);
    float d2 = __builtin_amdgcn_exp2f(0.2f * f2c);
    ED[hd * NROW + n] = (bf_bits(e2) << 16) | bf_bits(d2);
  }

#pragma unroll
  for (int c = 0; c < 4; ++c)
#pragma unroll
    for (int r = 0; r < 4; ++r)
      ht_tile[(c * 16 + kg * 4 + r) * 66 + wid * 16 + il] =
          __float2bfloat16(acc[c][r]);
  __syncthreads();
  {
    const int o = tid >> 2, q = tid & 3;
    bf16x8 t0 = *(const bf16x8*)(&ht_tile[o * 66 + q * 16]);
    bf16x8 t1 = *(const bf16x8*)(&ht_tile[o * 66 + q * 16 + 8]);
    __hip_bfloat16* dst = hT + (size_t)(hd * FOUT + o) * NROW + n0 + q * 16;
    *(bf16x8*)(dst)     = t0;
    *(bf16x8*)(dst + 8) = t1;
  }
}

// ---------------------------------------------------------------------------
// K3: attention partials, BARRIER-FREE inner loop.
// Block = 16 rows x 4 head-waves x 2048-m chunk. Each lane loads its own adj
// words (int4 pairs; L1-shared across the 4 waves) -> mask is a per-lane
// cmp+cndmask, no ballots, no LDS masks, no per-iter __syncthreads.
// Packed bf16 E2|D2 tables (4 heads x 2048 cols = 32 KB LDS, staged once).
// adj + hT register double-buffered (static A/B names).
// ---------------------------------------------------------------------------
__global__ __launch_bounds__(256, 3) void gat_attn(
    const int* __restrict__ adj, const __hip_bfloat16* __restrict__ hTg,
    const float* __restrict__ f1, const unsigned* __restrict__ EDg,
    float* __restrict__ part)
{
  constexpr int S = 4;
  constexpr int MCH = NROW / S;        // 2048
  constexpr int ITERS = MCH / 64;      // 32
  const int tid = threadIdx.x;
  const int wid = tid >> 6, lane = tid & 63;   // wid = head
  const int il = lane & 15, kg = lane >> 4;

  const int nwg = S * (NROW / 16);                 // 2048
  const int bid = (blockIdx.x & 7) * (nwg >> 3) + (blockIdx.x >> 3);
  const int rg = bid & 511, mc = bid >> 9;
  const int n0 = rg * 16;
  const int mbase = mc * MCH;

  __shared__ __align__(16) unsigned tbl[NHEAD * MCH];   // 32 KB (reused as ep)

  // stage packed tables (all heads)
#pragma unroll
  for (int q = 0; q < NHEAD * MCH / 1024; ++q) {
    int idx = (q * 256 + tid) * 4;
    int hd = idx >> 11, m = idx & (MCH - 1);
    *(u32x4*)(&tbl[idx]) = *(const u32x4*)(EDg + hd * NROW + mbase + m);
  }

  // per-lane row constants (row n0+il of this wave's head)
  const float f1v = f1[wid * NROW + n0 + il];
  const float E1  = __builtin_amdgcn_exp2f(f1v);
  const float D1  = __builtin_amdgcn_exp2f(0.2f * f1v);
  const float iE1 = __builtin_amdgcn_exp2f(-f1v);

  // per-lane adj pointer: row n0+il, col base mbase + kg*8
  const int* aprow = adj + (size_t)(n0 + il) * NROW + mbase + kg * 8;
  const __hip_bfloat16* hbase = hTg + (size_t)(wid * FOUT) * NROW + mbase;

  f32x4 acc[4], accD;
  {
    f32x4 z = {0.f, 0.f, 0.f, 0.f};
#pragma unroll
    for (int c = 0; c < 4; ++c) acc[c] = z;
    accD = z;
  }
  bf16x8 ones;
#pragma unroll
  for (int e = 0; e < 8; ++e) ones[e] = (__bf16)1.0f;

  // prologue: it=0 operands into A-regs (issued before the table barrier)
  i32x4 avA[4], avB[4];
  bf16x8 afrA[8], afrB[8];
#pragma unroll
  for (int ks = 0; ks < 2; ++ks)
#pragma unroll
    for (int h = 0; h < 2; ++h)
      avA[ks * 2 + h] = *(const i32x4*)(aprow + ks * 32 + h * 4);
#pragma unroll
  for (int ks = 0; ks < 2; ++ks)
#pragma unroll
    for (int c = 0; c < 4; ++c)
      afrA[ks * 4 + c] =
          *(const bf16x8*)(hbase + (c * 16 + il) * NROW + ks * 32 + kg * 8);

  __syncthreads();   // tables ready (the only barrier before the epilogue)

  auto body = [&](int it, i32x4 (&avC)[4], bf16x8 (&afrC)[8],
                  i32x4 (&avN)[4], bf16x8 (&afrN)[8]) {
    if (it + 1 < ITERS) {           // prefetch it+1 (stays in flight: no barrier)
#pragma unroll
      for (int ks = 0; ks < 2; ++ks)
#pragma unroll
        for (int h = 0; h < 2; ++h)
          avN[ks * 2 + h] =
              *(const i32x4*)(aprow + (it + 1) * 64 + ks * 32 + h * 4);
#pragma unroll
      for (int ks = 0; ks < 2; ++ks)
#pragma unroll
        for (int c = 0; c < 4; ++c)
          afrN[ks * 4 + c] = *(const bf16x8*)(
              hbase + (c * 16 + il) * NROW + (it + 1) * 64 + ks * 32 + kg * 8);
    }
#pragma unroll
    for (int ks = 0; ks < 2; ++ks) {
      const unsigned* tb = &tbl[wid * MCH + it * 64 + ks * 32 + kg * 8];
      u32x4 wa = *(const u32x4*)(tb);
      u32x4 wb = *(const u32x4*)(tb + 4);
      float p[8];
#pragma unroll
      for (int e = 0; e < 8; ++e) {
        unsigned wv = (e < 4) ? wa[e] : wb[e - 4];
        float Ef = __uint_as_float(wv & 0xFFFF0000u);
        float Df = __uint_as_float(wv << 16);
        bool neg = Ef < iE1;                     // s < 0
        float c2 = neg ? Df : Ef;
        float c1 = neg ? D1 : E1;
        float q = c1 * c2;
        int adjv = (e < 4) ? avC[ks * 2][e] : avC[ks * 2 + 1][e - 4];
        p[e] = (adjv != 0) ? q : 0.0f;
      }
      bf16x8 pb;
#pragma unroll
      for (int e = 0; e < 8; ++e) pb[e] = (__bf16)p[e];
#pragma unroll
      for (int c = 0; c < 4; ++c)
        acc[c] = __builtin_amdgcn_mfma_f32_16x16x32_bf16(
            afrC[ks * 4 + c], pb, acc[c], 0, 0, 0);
      accD = __builtin_amdgcn_mfma_f32_16x16x32_bf16(ones, pb, accD, 0, 0, 0);
    }
  };

  for (int it = 0; it < ITERS; it += 2) {
    body(it,     avA, afrA, avB, afrB);
    body(it + 1, avB, afrB, avA, afrA);
  }

  // ---- epilogue: wave-private LDS transpose (reuse tbl), coalesced stores
  __syncthreads();                       // all waves done reading tables
  float* ep = (float*)tbl;
  float* wep = ep + wid * (65 * 17);     // stride-17 rows: no 4-way conflicts
#pragma unroll
  for (int c = 0; c < 4; ++c)
#pragma unroll
    for (int r = 0; r < 4; ++r)
      wep[(c * 16 + kg * 4 + r) * 17 + il] = acc[c][r];
  if (kg == 0) wep[64 * 17 + il] = accD[0];
  __builtin_amdgcn_s_waitcnt(0);         // ds writes complete (same wave)

  const int og = lane >> 4, nl = lane & 15;
  float* pp = part + ((size_t)(mc * NHEAD + wid) * 65) * NROW + n0 + nl;
#pragma unroll
  for (int j = 0; j < 16; ++j) {
    int col = j * 4 + og;
    pp[(size_t)col * NROW] = wep[col * 17 + nl];
  }
  if (og == 0) pp[(size_t)64 * NROW] = wep[64 * 17 + nl];
}

// ---------------------------------------------------------------------------
// K4: combine 4 partial slices (column-major layout), divide, sigmoid, store.
// ---------------------------------------------------------------------------
__global__ __launch_bounds__(256) void gat_comb(
    const float* __restrict__ part, float* __restrict__ out)
{
  constexpr int S = 4;
  const int tid = threadIdx.x;
  const int hd = blockIdx.x & 3, nc = blockIdx.x >> 2;
  const int nl = tid >> 2, oq = tid & 3;
  const int n = nc * 64 + nl;

  float num[16];
#pragma unroll
  for (int c = 0; c < 16; ++c) num[c] = 0.f;
  float den = 0.f;

#pragma unroll
  for (int s = 0; s < S; ++s) {
    const float* pb = part + ((size_t)(s * NHEAD + hd) * 65) * NROW + n;
#pragma unroll
    for (int c = 0; c < 16; ++c)
      num[c] += pb[(size_t)(oq * 16 + c) * NROW];
    den += pb[(size_t)64 * NROW];
  }

  float invL = 1.0f / den;
  float* op = out + (size_t)n * (NHEAD * FOUT) + hd * FOUT + oq * 16;
#pragma unroll
  for (int g = 0; g < 4; ++g) {
    f32x4 r;
#pragma unroll
    for (int j = 0; j < 4; ++j)
      r[j] = 1.0f /
             (1.0f + __builtin_amdgcn_exp2f(-num[g * 4 + j] * invL * LOG2E));
    *(f32x4*)(op + g * 4) = r;
  }
}

extern "C" void kernel_launch(void* const* d_in, const int* in_sizes, int n_in,
                              void* d_out, int out_size, void* d_ws, size_t ws_size,
                              hipStream_t stream) {
  const float* x   = (const float*)d_in[0];
  const int*   adj = (const int*)d_in[1];
  const float* W   = (const float*)d_in[2];
  const float* a1  = (const float*)d_in[3];
  const float* a2  = (const float*)d_in[4];
  float* out = (float*)d_out;

  char* ws = (char*)d_ws;
  const size_t WT_OFF = 0;
  const size_t HT_OFF = WT_OFF + (size_t)NHEAD * FOUT * FIN * 2;     // 256 KB
  const size_t F1_OFF = HT_OFF + (size_t)NHEAD * FOUT * NROW * 2;    // 4 MB
  const size_t ED_OFF = F1_OFF + (size_t)NHEAD * NROW * 4;           // 128 KB
  const size_t PT_OFF = ED_OFF + (size_t)NHEAD * NROW * 4;           // 128 KB
  // part: [4][NHEAD][65][NROW] f32 = 34.1 MB; total ~38.6 MB

  __hip_bfloat16* WT = (__hip_bfloat16*)(ws + WT_OFF);
  __hip_bfloat16* hT = (__hip_bfloat16*)(ws + HT_OFF);
  float* f1 = (float*)(ws + F1_OFF);
  unsigned* ED = (unsigned*)(ws + ED_OFF);
  float* part = (float*)(ws + PT_OFF);

  wt_build<<<8, 256, 0, stream>>>(W, WT);
  gat_proj<<<NHEAD * (NROW / 64), 256, 0, stream>>>(x, WT, a1, a2, hT, f1, ED);
  gat_attn<<<4 * (NROW / 16), 256, 0, stream>>>(adj, hT, f1, ED, part);
  gat_comb<<<(NROW / 64) * NHEAD, 256, 0, stream>>>(part, out);
}

// Round 9
// 175.550 us; speedup vs baseline: 2.2319x; 2.2319x over previous
//
#include <hip/hip_runtime.h>
#include <hip/hip_bf16.h>

#define NROW 8192
#define FIN  512
#define FOUT 64
#define NHEAD 4

constexpr float LOG2E = 1.44269504088896f;

typedef float f32x4 __attribute__((ext_vector_type(4)));
typedef __bf16 bf16x8 __attribute__((ext_vector_type(8)));

// ---------------------------------------------------------------------------
// K0: WT[hd][o][f] = bf16(W[hd][f][o])
// ---------------------------------------------------------------------------
__global__ __launch_bounds__(256) void wt_build(
    const float* __restrict__ W, __hip_bfloat16* __restrict__ WT)
{
  int t = blockIdx.x * 256 + threadIdx.x;
  int hd = t >> 9, f = t & 511;
  const float* wp = W + (hd * FIN + f) * FOUT;
#pragma unroll 8
  for (int o = 0; o < FOUT; ++o)
    WT[(hd * FOUT + o) * FIN + f] = __float2bfloat16(wp[o]);
}

// ---------------------------------------------------------------------------
// K1: h = x*W via MFMA. Block = one head, 4 waves, 64 n-rows.
// WT head staged once in XOR-swizzled LDS; epilogue transposes hT through LDS
// for coalesced stores. (R6-verified)
// ---------------------------------------------------------------------------
__global__ __launch_bounds__(256) void gat_proj(
    const float* __restrict__ x, const __hip_bfloat16* __restrict__ WT,
    const float* __restrict__ a1, const float* __restrict__ a2,
    __hip_bfloat16* __restrict__ hT, float* __restrict__ f1,
    float* __restrict__ E2, float* __restrict__ D2)
{
  const int tid = threadIdx.x;
  const int wid = tid >> 6, lane = tid & 63;
  const int il = lane & 15, kg = lane >> 4;
  const int hd = blockIdx.x & 3;
  const int rg = blockIdx.x >> 2;
  const int n0 = rg * 64;

  __shared__ __align__(16) __hip_bfloat16 wt_lds[64 * 512];   // 64 KB
  __shared__ __align__(16) __hip_bfloat16 ht_tile[64 * 66];   // 8.25 KB

  {
    const int o = tid >> 2, q = tid & 3;
    const __hip_bfloat16* src = WT + (size_t)(hd * FOUT + o) * FIN;
#pragma unroll
    for (int k = 0; k < 16; ++k) {
      int u = q * 16 + k;
      bf16x8 vv = *(const bf16x8*)(src + u * 8);
      *(bf16x8*)(&wt_lds[o * 512 + (u ^ (o & 7)) * 8]) = vv;
    }
  }
  __syncthreads();

  const int n = n0 + wid * 16 + il;
  const float* xp = x + (size_t)n * FIN + kg * 8;

  f32x4 acc[4];
#pragma unroll
  for (int c = 0; c < 4; ++c) { f32x4 z = {0.f,0.f,0.f,0.f}; acc[c] = z; }

#pragma unroll 4
  for (int kk = 0; kk < FIN / 32; ++kk) {
    f32x4 xl = *(const f32x4*)(xp + kk * 32);
    f32x4 xh = *(const f32x4*)(xp + kk * 32 + 4);
    bf16x8 xb;
#pragma unroll
    for (int e = 0; e < 4; ++e) {
      xb[e]     = (__bf16)xl[e];
      xb[4 + e] = (__bf16)xh[e];
    }
#pragma unroll
    for (int c = 0; c < 4; ++c) {
      const int o = c * 16 + il;
      bf16x8 af = *(const bf16x8*)(
          &wt_lds[o * 512 + ((kk * 4 + kg) ^ (il & 7)) * 8]);
      acc[c] = __builtin_amdgcn_mfma_f32_16x16x32_bf16(af, xb, acc[c], 0, 0, 0);
    }
  }

  float p1 = 0.f, p2 = 0.f;
#pragma unroll
  for (int c = 0; c < 4; ++c) {
    f32x4 a1v = *(const f32x4*)(a1 + hd * FOUT + c * 16 + kg * 4);
    f32x4 a2v = *(const f32x4*)(a2 + hd * FOUT + c * 16 + kg * 4);
#pragma unroll
    for (int r = 0; r < 4; ++r) {
      p1 = fmaf(acc[c][r], a1v[r], p1);
      p2 = fmaf(acc[c][r], a2v[r], p2);
    }
  }
  p1 += __shfl_xor(p1, 16); p1 += __shfl_xor(p1, 32);
  p2 += __shfl_xor(p2, 16); p2 += __shfl_xor(p2, 32);
  if (kg == 0) {
    float f1c = p1 * LOG2E;
    float f2c = p2 * LOG2E;
    f1[hd * NROW + n] = f1c;
    E2[hd * NROW + n] = __builtin_amdgcn_exp2f(f2c);
    D2[hd * NROW + n] = __builtin_amdgcn_exp2f(0.2f * f2c);
  }

#pragma unroll
  for (int c = 0; c < 4; ++c)
#pragma unroll
    for (int r = 0; r < 4; ++r)
      ht_tile[(c * 16 + kg * 4 + r) * 66 + wid * 16 + il] =
          __float2bfloat16(acc[c][r]);
  __syncthreads();
  {
    const int o = tid >> 2, q = tid & 3;
    bf16x8 t0 = *(const bf16x8*)(&ht_tile[o * 66 + q * 16]);
    bf16x8 t1 = *(const bf16x8*)(&ht_tile[o * 66 + q * 16 + 8]);
    __hip_bfloat16* dst = hT + (size_t)(hd * FOUT + o) * NROW + n0 + q * 16;
    *(bf16x8*)(dst)     = t0;
    *(bf16x8*)(dst + 8) = t1;
  }
}

// ---------------------------------------------------------------------------
// K3: attention partials = the R4-R6 42us loop + WAVE-PRIVATE inline ballot
// masks (mask_build/mw eliminated).
// Block = 4 waves, SAME head, 64 rows (wave owns 16), 2048-m chunk.
//  - adj loaded coalescedly (lane = column, 16 x 4B narrow loads per iter),
//    one iter ahead in registers; __ballot -> lane0 ds_write_b64 into a tiny
//    wave-private double-buffered slot; consumed next iter via one broadcast
//    ds_read_b64. No extra barriers beyond the existing 1/iter.
//  - E2/D2 chunk tables in LDS (staged once); hT tile [64o][64m] XOR-swizzled
//    LDS, double-buffered, reg-prefetched.
//  - p = adjmask & max(E1*E2, D1*D2)   (exp2(lrelu(s)) == max of the pieces)
// Grid 2048, head fastest post-swizzle: the 4 head-blocks sharing an adj
// chunk land on the same XCD -> adj HBM-read exactly once.
// ---------------------------------------------------------------------------
__global__ __launch_bounds__(256, 4) void gat_attn(
    const int* __restrict__ adj, const __hip_bfloat16* __restrict__ hTg,
    const float* __restrict__ f1, const float* __restrict__ E2g,
    const float* __restrict__ D2g, float* __restrict__ part)
{
  constexpr int S = 4;
  constexpr int MCH = NROW / S;        // 2048
  constexpr int ITERS = MCH / 64;      // 32
  const int tid = threadIdx.x;
  const int wid = tid >> 6, lane = tid & 63;
  const int il = lane & 15, kg = lane >> 4;

  const int nwg = S * NHEAD * 128;                 // 2048
  const int bid = (blockIdx.x & 7) * (nwg >> 3) + (blockIdx.x >> 3);
  const int hd = bid & 3;
  const int rg = (bid >> 2) & 127;
  const int mc = bid >> 9;
  const int n0 = rg * 64;
  const int n  = n0 + wid * 16 + il;
  const int mbase = mc * MCH;

  __shared__ __align__(16) __hip_bfloat16 lds[2][64 * 64];   // 16 KB
  __shared__ __align__(16) float lds_e[MCH];                 // 8 KB
  __shared__ __align__(16) float lds_d[MCH];                 // 8 KB
  __shared__ __align__(8) unsigned lmask[NHEAD][2][16][2];   // 1 KB

  const float f1v = f1[hd * NROW + n];
  const float E1  = __builtin_amdgcn_exp2f(f1v);
  const float D1  = __builtin_amdgcn_exp2f(0.2f * f1v);

  const float* E2p = E2g + hd * NROW + mbase;
  const float* D2p = D2g + hd * NROW + mbase;

  // hT tile staging map (R4-verified)
  const int so = tid >> 2, sq = tid & 3;
  const __hip_bfloat16* hs = hTg + (size_t)(hd * FOUT + so) * NROW + mbase + sq * 16;
  const int w0off = so * 64 + ((2 * sq)     ^ (so & 7)) * 8;
  const int w1off = so * 64 + ((2 * sq + 1) ^ (so & 7)) * 8;

  // wave-private adj rows (coalesced: lane = column)
  const int* ap = adj + (size_t)(n0 + wid * 16) * NROW + mbase;

  f32x4 acc[5];
#pragma unroll
  for (int c = 0; c < 5; ++c) { f32x4 z = {0.f,0.f,0.f,0.f}; acc[c] = z; }

  bf16x8 ones;
#pragma unroll
  for (int e = 0; e < 8; ++e) ones[e] = (__bf16)1.0f;

  // ---- prologue
  int av[16];
#pragma unroll
  for (int r = 0; r < 16; ++r) av[r] = ap[(size_t)r * NROW + lane];

  // stage tables + tile 0 (overlaps with av latency)
#pragma unroll
  for (int q = 0; q < MCH / 1024; ++q) {
    int idx = (q * 256 + tid) * 4;
    *(f32x4*)(&lds_e[idx]) = *(const f32x4*)(E2p + idx);
    *(f32x4*)(&lds_d[idx]) = *(const f32x4*)(D2p + idx);
  }
  {
    bf16x8 s0 = *(const bf16x8*)(hs);
    bf16x8 s1 = *(const bf16x8*)(hs + 8);
    *(bf16x8*)(&lds[0][w0off]) = s0;
    *(bf16x8*)(&lds[0][w1off]) = s1;
  }

  // masks for it=0 (wave-private, no barrier needed)
#pragma unroll
  for (int r = 0; r < 16; ++r) {
    unsigned long long b = __ballot(av[r] != 0);
    if (lane == 0) *(unsigned long long*)&lmask[wid][0][r][0] = b;
  }
  // av <- it=1
#pragma unroll
  for (int r = 0; r < 16; ++r) av[r] = ap[(size_t)r * NROW + 64 + lane];

  __syncthreads();

  for (int it = 0; it < ITERS; ++it) {
    const int cur = it & 1, nxt = cur ^ 1;
    const bool more = (it + 1 < ITERS);

    bf16x8 s0n, s1n;
    if (more) {                         // hT tile it+1 -> regs (in flight)
      s0n = *(const bf16x8*)(hs + (it + 1) * 64);
      s1n = *(const bf16x8*)(hs + (it + 1) * 64 + 8);
    }

    // ballots for it+1 (consume av), then refill av with it+2
    if (more) {
#pragma unroll
      for (int r = 0; r < 16; ++r) {
        unsigned long long b = __ballot(av[r] != 0);
        if (lane == 0) *(unsigned long long*)&lmask[wid][nxt][r][0] = b;
      }
    }
    if (it + 2 < ITERS) {
#pragma unroll
      for (int r = 0; r < 16; ++r)
        av[r] = ap[(size_t)r * NROW + (it + 2) * 64 + lane];
    }

    // this wave's mask word for row il (broadcast read, written last iter)
    unsigned long long w64 =
        *(const unsigned long long*)&lmask[wid][cur][il][0];

#pragma unroll
    for (int ks = 0; ks < 2; ++ks) {
      unsigned mvs = (unsigned)(w64 >> (ks * 32)) >> (kg * 8);
      const int mof = it * 64 + ks * 32 + kg * 8;
      f32x4 e2l = *(const f32x4*)(&lds_e[mof]);
      f32x4 e2h = *(const f32x4*)(&lds_e[mof + 4]);
      f32x4 d2l = *(const f32x4*)(&lds_d[mof]);
      f32x4 d2h = *(const f32x4*)(&lds_d[mof + 4]);

      bf16x8 afr[4];
#pragma unroll
      for (int c = 0; c < 4; ++c) {
        const int row = c * 16 + il;
        afr[c] = *(const bf16x8*)(
            &lds[cur][row * 64 + ((ks * 4 + kg) ^ (il & 7)) * 8]);
      }

      float p[8];
#pragma unroll
      for (int e = 0; e < 8; ++e) {
        float E2v = (e < 4) ? e2l[e] : e2h[e - 4];
        float D2v = (e < 4) ? d2l[e] : d2h[e - 4];
        float q = fmaxf(E1 * E2v, D1 * D2v);        // exp2(lrelu(s))
        int msk = ((int)(mvs << (31 - e))) >> 31;   // adj bit -> 0 / -1
        p[e] = __uint_as_float(__float_as_uint(q) & (unsigned)msk);
      }
      bf16x8 pb;
#pragma unroll
      for (int e = 0; e < 8; ++e) pb[e] = (__bf16)p[e];

#pragma unroll
      for (int c = 0; c < 4; ++c)
        acc[c] = __builtin_amdgcn_mfma_f32_16x16x32_bf16(afr[c], pb, acc[c], 0, 0, 0);
      acc[4] = __builtin_amdgcn_mfma_f32_16x16x32_bf16(ones, pb, acc[4], 0, 0, 0);
    }

    if (more) {
      *(bf16x8*)(&lds[nxt][w0off]) = s0n;
      *(bf16x8*)(&lds[nxt][w1off]) = s1n;
      __syncthreads();
    }
  }

  // ---- epilogue (R4-verified layout)
  float* pp = part + ((size_t)((mc * NHEAD + hd) * NROW + n)) * 68;
#pragma unroll
  for (int c = 0; c < 4; ++c)
    *(f32x4*)(pp + c * 16 + kg * 4) = acc[c];
  if (kg == 0) pp[64] = acc[4][0];
}

// ---------------------------------------------------------------------------
// K4: combine S partial slices, divide, sigmoid, write out.
// ---------------------------------------------------------------------------
__global__ __launch_bounds__(256) void gat_comb(
    const float* __restrict__ part, float* __restrict__ out, int S)
{
  int flat = blockIdx.x * 256 + threadIdx.x;
  int n = flat >> 6, c4 = flat & 63;
  int hd = c4 >> 4, o4 = (c4 & 15) * 4;
  f32x4 num = {0.f,0.f,0.f,0.f};
  float L = 0.f;
  for (int s = 0; s < S; ++s) {
    const float* pp = part + ((size_t)((s * NHEAD + hd) * NROW + n)) * 68;
    f32x4 v = *(const f32x4*)(pp + o4);
    num += v;
    L += pp[64];
  }
  float invL = 1.0f / L;
  f32x4 r;
#pragma unroll
  for (int j = 0; j < 4; ++j)
    r[j] = 1.0f / (1.0f + __builtin_amdgcn_exp2f(-num[j] * invL * LOG2E));
  *(f32x4*)(out + (size_t)n * (NHEAD * FOUT) + hd * FOUT + o4) = r;
}

extern "C" void kernel_launch(void* const* d_in, const int* in_sizes, int n_in,
                              void* d_out, int out_size, void* d_ws, size_t ws_size,
                              hipStream_t stream) {
  const float* x   = (const float*)d_in[0];
  const int*   adj = (const int*)d_in[1];
  const float* W   = (const float*)d_in[2];
  const float* a1  = (const float*)d_in[3];
  const float* a2  = (const float*)d_in[4];
  float* out = (float*)d_out;

  char* ws = (char*)d_ws;
  const size_t WT_OFF = 0;
  const size_t HT_OFF = WT_OFF + (size_t)NHEAD * FOUT * FIN * 2;     // 256 KB
  const size_t F1_OFF = HT_OFF + (size_t)NHEAD * FOUT * NROW * 2;    // 4 MB
  const size_t E2_OFF = F1_OFF + (size_t)NHEAD * NROW * 4;
  const size_t D2_OFF = E2_OFF + (size_t)NHEAD * NROW * 4;
  const size_t PT_OFF = D2_OFF + (size_t)NHEAD * NROW * 4;
  // part: [4][NHEAD][NROW][68] f32 = 35.7 MB; total ~40 MB

  __hip_bfloat16* WT = (__hip_bfloat16*)(ws + WT_OFF);
  __hip_bfloat16* hT = (__hip_bfloat16*)(ws + HT_OFF);
  float* f1 = (float*)(ws + F1_OFF);
  float* E2 = (float*)(ws + E2_OFF);
  float* D2 = (float*)(ws + D2_OFF);
  float* part = (float*)(ws + PT_OFF);

  wt_build<<<8, 256, 0, stream>>>(W, WT);
  gat_proj<<<NHEAD * (NROW / 64), 256, 0, stream>>>(x, WT, a1, a2, hT, f1, E2, D2);
  gat_attn<<<4 * NHEAD * 128, 256, 0, stream>>>(adj, hT, f1, E2, D2, part);
  gat_comb<<<NROW * NHEAD * FOUT / 4 / 256, 256, 0, stream>>>(part, out, 4);
}

// Round 10
// 155.197 us; speedup vs baseline: 2.5246x; 1.1311x over previous
//
#include <hip/hip_runtime.h>
#include <hip/hip_bf16.h>

#define NROW 8192
#define FIN  512
#define FOUT 64
#define NHEAD 4

constexpr float LOG2E = 1.44269504088896f;

typedef float f32x4 __attribute__((ext_vector_type(4)));
typedef int   i32x4 __attribute__((ext_vector_type(4)));
typedef unsigned u32x4 __attribute__((ext_vector_type(4)));
typedef __bf16 bf16x8 __attribute__((ext_vector_type(8)));

__device__ __forceinline__ unsigned bf_bits(float x) {
  unsigned u = __float_as_uint(x);
  u += 0x7FFF + ((u >> 16) & 1);          // round-to-nearest-even
  return u >> 16;
}

// ---------------------------------------------------------------------------
// K0: WT[hd][o][f] = bf16(W[hd][f][o])
// ---------------------------------------------------------------------------
__global__ __launch_bounds__(256) void wt_build(
    const float* __restrict__ W, __hip_bfloat16* __restrict__ WT)
{
  int t = blockIdx.x * 256 + threadIdx.x;
  int hd = t >> 9, f = t & 511;
  const float* wp = W + (hd * FIN + f) * FOUT;
#pragma unroll 8
  for (int o = 0; o < FOUT; ++o)
    WT[(hd * FOUT + o) * FIN + f] = __float2bfloat16(wp[o]);
}

// ---------------------------------------------------------------------------
// K1: h = x*W via MFMA (R8-verified). Emits hT, f1, and packed table
// ED[hd][n] = (bf16(exp2(f2c)) << 16) | bf16(exp2(0.2*f2c)).
// ---------------------------------------------------------------------------
__global__ __launch_bounds__(256) void gat_proj(
    const float* __restrict__ x, const __hip_bfloat16* __restrict__ WT,
    const float* __restrict__ a1, const float* __restrict__ a2,
    __hip_bfloat16* __restrict__ hT, float* __restrict__ f1,
    unsigned* __restrict__ ED)
{
  const int tid = threadIdx.x;
  const int wid = tid >> 6, lane = tid & 63;
  const int il = lane & 15, kg = lane >> 4;
  const int hd = blockIdx.x & 3;
  const int rg = blockIdx.x >> 2;
  const int n0 = rg * 64;

  __shared__ __align__(16) __hip_bfloat16 wt_lds[64 * 512];   // 64 KB
  __shared__ __align__(16) __hip_bfloat16 ht_tile[64 * 66];   // 8.25 KB

  {
    const int o = tid >> 2, q = tid & 3;
    const __hip_bfloat16* src = WT + (size_t)(hd * FOUT + o) * FIN;
#pragma unroll
    for (int k = 0; k < 16; ++k) {
      int u = q * 16 + k;
      bf16x8 vv = *(const bf16x8*)(src + u * 8);
      *(bf16x8*)(&wt_lds[o * 512 + (u ^ (o & 7)) * 8]) = vv;
    }
  }
  __syncthreads();

  const int n = n0 + wid * 16 + il;
  const float* xp = x + (size_t)n * FIN + kg * 8;

  f32x4 acc[4];
#pragma unroll
  for (int c = 0; c < 4; ++c) { f32x4 z = {0.f,0.f,0.f,0.f}; acc[c] = z; }

#pragma unroll 4
  for (int kk = 0; kk < FIN / 32; ++kk) {
    f32x4 xl = *(const f32x4*)(xp + kk * 32);
    f32x4 xh = *(const f32x4*)(xp + kk * 32 + 4);
    bf16x8 xb;
#pragma unroll
    for (int e = 0; e < 4; ++e) {
      xb[e]     = (__bf16)xl[e];
      xb[4 + e] = (__bf16)xh[e];
    }
#pragma unroll
    for (int c = 0; c < 4; ++c) {
      const int o = c * 16 + il;
      bf16x8 af = *(const bf16x8*)(
          &wt_lds[o * 512 + ((kk * 4 + kg) ^ (il & 7)) * 8]);
      acc[c] = __builtin_amdgcn_mfma_f32_16x16x32_bf16(af, xb, acc[c], 0, 0, 0);
    }
  }

  float p1 = 0.f, p2 = 0.f;
#pragma unroll
  for (int c = 0; c < 4; ++c) {
    f32x4 a1v = *(const f32x4*)(a1 + hd * FOUT + c * 16 + kg * 4);
    f32x4 a2v = *(const f32x4*)(a2 + hd * FOUT + c * 16 + kg * 4);
#pragma unroll
    for (int r = 0; r < 4; ++r) {
      p1 = fmaf(acc[c][r], a1v[r], p1);
      p2 = fmaf(acc[c][r], a2v[r], p2);
    }
  }
  p1 += __shfl_xor(p1, 16); p1 += __shfl_xor(p1, 32);
  p2 += __shfl_xor(p2, 16); p2 += __shfl_xor(p2, 32);
  if (kg == 0) {
    float f1c = p1 * LOG2E;
    float f2c = p2 * LOG2E;
    f1[hd * NROW + n] = f1c;
    float e2 = __builtin_amdgcn_exp2f(f2c);
    float d2 = __builtin_amdgcn_exp2f(0.2f * f2c);
    ED[hd * NROW + n] = (bf_bits(e2) << 16) | bf_bits(d2);
  }

#pragma unroll
  for (int c = 0; c < 4; ++c)
#pragma unroll
    for (int r = 0; r < 4; ++r)
      ht_tile[(c * 16 + kg * 4 + r) * 66 + wid * 16 + il] =
          __float2bfloat16(acc[c][r]);
  __syncthreads();
  {
    const int o = tid >> 2, q = tid & 3;
    bf16x8 t0 = *(const bf16x8*)(&ht_tile[o * 66 + q * 16]);
    bf16x8 t1 = *(const bf16x8*)(&ht_tile[o * 66 + q * 16 + 8]);
    __hip_bfloat16* dst = hT + (size_t)(hd * FOUT + o) * NROW + n0 + q * 16;
    *(bf16x8*)(dst)     = t0;
    *(bf16x8*)(dst + 8) = t1;
  }
}

// ---------------------------------------------------------------------------
// K3: attention partials. R9 structure with two changes:
//  (1) nibble-transpose mask path: 4 int4 loads/iter (lane = row-quarter x
//      colgroup), pack nonzero-nibbles, 4 ds_write_b8 into a wave-private
//      double-buffered [16][16] byte array; reader: 2 ds_read_u16. No
//      ballots, no exec-masked writes, 4x fewer VMEM issues.
//  (2) packed bf16 E|D table in LDS (8 KB instead of 16).
// LDS 26 KB -> 6 blocks/CU (was 33 KB / ~3). Inner loop otherwise identical:
// hT XOR-swizzled dbuf tile, p = mask & max(E1*E2, D1*D2), 1 barrier/iter.
// ---------------------------------------------------------------------------
__global__ __launch_bounds__(256, 5) void gat_attn(
    const int* __restrict__ adj, const __hip_bfloat16* __restrict__ hTg,
    const float* __restrict__ f1, const unsigned* __restrict__ EDg,
    float* __restrict__ part)
{
  constexpr int S = 4;
  constexpr int MCH = NROW / S;        // 2048
  constexpr int ITERS = MCH / 64;      // 32
  const int tid = threadIdx.x;
  const int wid = tid >> 6, lane = tid & 63;
  const int il = lane & 15, kg = lane >> 4;

  const int nwg = S * NHEAD * 128;                 // 2048
  const int bid = (blockIdx.x & 7) * (nwg >> 3) + (blockIdx.x >> 3);
  const int hd = bid & 3;
  const int rg = (bid >> 2) & 127;
  const int mc = bid >> 9;
  const int n0 = rg * 64;
  const int n  = n0 + wid * 16 + il;
  const int mbase = mc * MCH;

  __shared__ __align__(16) __hip_bfloat16 lds[2][64 * 64];   // 16 KB
  __shared__ __align__(16) unsigned tblp[MCH];               // 8 KB
  __shared__ unsigned char nib[NHEAD][2][16][16];            // 2 KB

  const float f1v = f1[hd * NROW + n];
  const float E1  = __builtin_amdgcn_exp2f(f1v);
  const float D1  = __builtin_amdgcn_exp2f(0.2f * f1v);

  // hT tile staging map (verified)
  const int so = tid >> 2, sq = tid & 3;
  const __hip_bfloat16* hs =
      hTg + (size_t)(hd * FOUT + so) * NROW + mbase + sq * 16;
  const int w0off = so * 64 + ((2 * sq)     ^ (so & 7)) * 8;
  const int w1off = so * 64 + ((2 * sq + 1) ^ (so & 7)) * 8;

  // adj: lane covers (row-quarter lane>>4, colgroup lane&15)
  const int arow = lane >> 4, acg = lane & 15;
  const int* apn = adj + (size_t)(n0 + wid * 16 + arow) * NROW + mbase + acg * 4;

  f32x4 acc[5];
#pragma unroll
  for (int c = 0; c < 5; ++c) { f32x4 z = {0.f,0.f,0.f,0.f}; acc[c] = z; }

  bf16x8 ones;
#pragma unroll
  for (int e = 0; e < 8; ++e) ones[e] = (__bf16)1.0f;

  // ---- prologue
  i32x4 ld[4];
#pragma unroll
  for (int g = 0; g < 4; ++g)
    ld[g] = *(const i32x4*)(apn + (size_t)(g * 4) * NROW);

  // stage packed table (this head's chunk) + tile 0
#pragma unroll
  for (int q = 0; q < MCH / 1024; ++q) {
    int idx = (q * 256 + tid) * 4;
    *(u32x4*)(&tblp[idx]) = *(const u32x4*)(EDg + hd * NROW + mbase + idx);
  }
  {
    bf16x8 s0 = *(const bf16x8*)(hs);
    bf16x8 s1 = *(const bf16x8*)(hs + 8);
    *(bf16x8*)(&lds[0][w0off]) = s0;
    *(bf16x8*)(&lds[0][w1off]) = s1;
  }

  // pack it=0 nibbles into buf 0
#pragma unroll
  for (int g = 0; g < 4; ++g) {
    unsigned nv = min((unsigned)ld[g][0], 1u)
                | (min((unsigned)ld[g][1], 1u) << 1)
                | (min((unsigned)ld[g][2], 1u) << 2)
                | (min((unsigned)ld[g][3], 1u) << 3);
    nib[wid][0][g * 4 + arow][acg] = (unsigned char)nv;
  }
  // ld <- it=1
#pragma unroll
  for (int g = 0; g < 4; ++g)
    ld[g] = *(const i32x4*)(apn + (size_t)(g * 4) * NROW + 64);

  __syncthreads();

  for (int it = 0; it < ITERS; ++it) {
    const int cur = it & 1, nxt = cur ^ 1;
    const bool more = (it + 1 < ITERS);

    // read this wave's mask bytes for row il (dbuf: safe vs nxt writes)
    unsigned short t0 = *(const unsigned short*)&nib[wid][cur][il][kg * 2];
    unsigned short t1 = *(const unsigned short*)&nib[wid][cur][il][8 + kg * 2];

    bf16x8 s0n, s1n;
    if (more) {                          // hT tile it+1 -> regs (in flight)
      s0n = *(const bf16x8*)(hs + (it + 1) * 64);
      s1n = *(const bf16x8*)(hs + (it + 1) * 64 + 8);
    }

    // pack it+1 nibbles (consume ld), write to nxt buffer
    if (more) {
#pragma unroll
      for (int g = 0; g < 4; ++g) {
        unsigned nv = min((unsigned)ld[g][0], 1u)
                    | (min((unsigned)ld[g][1], 1u) << 1)
                    | (min((unsigned)ld[g][2], 1u) << 2)
                    | (min((unsigned)ld[g][3], 1u) << 3);
        nib[wid][nxt][g * 4 + arow][acg] = (unsigned char)nv;
      }
    }
    // ld <- it+2
    if (it + 2 < ITERS) {
#pragma unroll
      for (int g = 0; g < 4; ++g)
        ld[g] = *(const i32x4*)(apn + (size_t)(g * 4) * NROW + (it + 2) * 64);
    }

#pragma unroll
    for (int ks = 0; ks < 2; ++ks) {
      unsigned short tt = ks ? t1 : t0;
      unsigned m8 = ((unsigned)tt & 0xFu) | (((unsigned)tt >> 4) & 0xF0u);
      const int mof = it * 64 + ks * 32 + kg * 8;
      u32x4 wa = *(const u32x4*)(&tblp[mof]);
      u32x4 wb = *(const u32x4*)(&tblp[mof + 4]);

      bf16x8 afr[4];
#pragma unroll
      for (int c = 0; c < 4; ++c) {
        const int row = c * 16 + il;
        afr[c] = *(const bf16x8*)(
            &lds[cur][row * 64 + ((ks * 4 + kg) ^ (il & 7)) * 8]);
      }

      float p[8];
#pragma unroll
      for (int e = 0; e < 8; ++e) {
        unsigned wv = (e < 4) ? wa[e] : wb[e - 4];
        float Ef = __uint_as_float(wv & 0xFFFF0000u);
        float Df = __uint_as_float(wv << 16);
        float q = fmaxf(E1 * Ef, D1 * Df);            // exp2(lrelu(s))
        int msk = ((int)(m8 << (31 - e))) >> 31;      // adj bit -> 0 / -1
        p[e] = __uint_as_float(__float_as_uint(q) & (unsigned)msk);
      }
      bf16x8 pb;
#pragma unroll
      for (int e = 0; e < 8; ++e) pb[e] = (__bf16)p[e];

#pragma unroll
      for (int c = 0; c < 4; ++c)
        acc[c] = __builtin_amdgcn_mfma_f32_16x16x32_bf16(afr[c], pb, acc[c], 0, 0, 0);
      acc[4] = __builtin_amdgcn_mfma_f32_16x16x32_bf16(ones, pb, acc[4], 0, 0, 0);
    }

    if (more) {
      *(bf16x8*)(&lds[nxt][w0off]) = s0n;
      *(bf16x8*)(&lds[nxt][w1off]) = s1n;
      __syncthreads();
    }
  }

  // ---- epilogue (verified layout; L2 write-combines the strided pieces)
  float* pp = part + ((size_t)((mc * NHEAD + hd) * NROW + n)) * 68;
#pragma unroll
  for (int c = 0; c < 4; ++c)
    *(f32x4*)(pp + c * 16 + kg * 4) = acc[c];
  if (kg == 0) pp[64] = acc[4][0];
}

// ---------------------------------------------------------------------------
// K4: combine S partial slices, divide, sigmoid, write out.
// ---------------------------------------------------------------------------
__global__ __launch_bounds__(256) void gat_comb(
    const float* __restrict__ part, float* __restrict__ out, int S)
{
  int flat = blockIdx.x * 256 + threadIdx.x;
  int n = flat >> 6, c4 = flat & 63;
  int hd = c4 >> 4, o4 = (c4 & 15) * 4;
  f32x4 num = {0.f,0.f,0.f,0.f};
  float L = 0.f;
  for (int s = 0; s < S; ++s) {
    const float* pp = part + ((size_t)((s * NHEAD + hd) * NROW + n)) * 68;
    f32x4 v = *(const f32x4*)(pp + o4);
    num += v;
    L += pp[64];
  }
  float invL = 1.0f / L;
  f32x4 r;
#pragma unroll
  for (int j = 0; j < 4; ++j)
    r[j] = 1.0f / (1.0f + __builtin_amdgcn_exp2f(-num[j] * invL * LOG2E));
  *(f32x4*)(out + (size_t)n * (NHEAD * FOUT) + hd * FOUT + o4) = r;
}

extern "C" void kernel_launch(void* const* d_in, const int* in_sizes, int n_in,
                              void* d_out, int out_size, void* d_ws, size_t ws_size,
                              hipStream_t stream) {
  const float* x   = (const float*)d_in[0];
  const int*   adj = (const int*)d_in[1];
  const float* W   = (const float*)d_in[2];
  const float* a1  = (const float*)d_in[3];
  const float* a2  = (const float*)d_in[4];
  float* out = (float*)d_out;

  char* ws = (char*)d_ws;
  const size_t WT_OFF = 0;
  const size_t HT_OFF = WT_OFF + (size_t)NHEAD * FOUT * FIN * 2;     // 256 KB
  const size_t F1_OFF = HT_OFF + (size_t)NHEAD * FOUT * NROW * 2;    // 4 MB
  const size_t ED_OFF = F1_OFF + (size_t)NHEAD * NROW * 4;           // 128 KB
  const size_t PT_OFF = ED_OFF + (size_t)NHEAD * NROW * 4;           // 128 KB
  // part: [4][NHEAD][NROW][68] f32 = 35.7 MB; total ~40 MB

  __hip_bfloat16* WT = (__hip_bfloat16*)(ws + WT_OFF);
  __hip_bfloat16* hT = (__hip_bfloat16*)(ws + HT_OFF);
  float* f1 = (float*)(ws + F1_OFF);
  unsigned* ED = (unsigned*)(ws + ED_OFF);
  float* part = (float*)(ws + PT_OFF);

  wt_build<<<8, 256, 0, stream>>>(W, WT);
  gat_proj<<<NHEAD * (NROW / 64), 256, 0, stream>>>(x, WT, a1, a2, hT, f1, ED);
  gat_attn<<<4 * NHEAD * 128, 256, 0, stream>>>(adj, hT, f1, ED, part);
  gat_comb<<<NROW * NHEAD * FOUT / 4 / 256, 256, 0, stream>>>(part, out, 4);
}